// Round 1
// baseline (1420.833 us; speedup 1.0000x reference)
//
#include <hip/hip_runtime.h>
#include <math.h>

#define BB 4
#define NN 2048
#define KK 20

static __device__ __forceinline__ float lrelu(float z) {
    return z >= 0.f ? z : 0.2f * z;
}

// ---------------- sq: per-point squared norm ----------------
template<int C>
__global__ __launch_bounds__(256) void sq_kernel(const float* __restrict__ x,
                                                 float* __restrict__ sq) {
    int i = blockIdx.x * 256 + threadIdx.x;
    if (i >= BB * NN) return;
    int b = i / NN, n = i - b * NN;
    const float* xb = x + (size_t)b * C * NN + n;
    float s = 0.f;
    #pragma unroll
    for (int c = 0; c < C; ++c) {
        float v = xb[(size_t)c * NN];
        s = fmaf(v, v, s);
    }
    sq[i] = s;
}

// ---------------- knn: top-20 smallest distance indices ----------------
// Block = 256 threads handles (b, 8 consecutive queries).
// Thread t owns candidates j = t + s*256, s in 0..7 (registers, static idx only).
template<int C>
__global__ __launch_bounds__(256) void knn_kernel(const float* __restrict__ x,
                                                  const float* __restrict__ sq,
                                                  int* __restrict__ idx) {
    const int QT = 8;
    int blk = blockIdx.x;
    int b = blk / (NN / QT);
    int q0 = (blk - b * (NN / QT)) * QT;
    int t = threadIdx.x;
    __shared__ float xq[QT][C];
    __shared__ float sqq[QT];
    __shared__ float red_v[4];
    __shared__ int red_j[4];
    __shared__ int win;

    const float* xb = x + (size_t)b * C * NN;
    for (int e = t; e < QT * C; e += 256) {
        int q = e / C, c = e - q * C;
        xq[q][c] = xb[(size_t)c * NN + q0 + q];
    }
    if (t < QT) sqq[t] = sq[b * NN + q0 + t];
    __syncthreads();

    float acc[QT][8];
    #pragma unroll
    for (int q = 0; q < QT; ++q)
        #pragma unroll
        for (int s = 0; s < 8; ++s) acc[q][s] = 0.f;

    for (int c = 0; c < C; ++c) {
        float xj[8];
        #pragma unroll
        for (int s = 0; s < 8; ++s) xj[s] = xb[(size_t)c * NN + t + s * 256];
        #pragma unroll
        for (int q = 0; q < QT; ++q) {
            float xqc = xq[q][c];
            #pragma unroll
            for (int s = 0; s < 8; ++s) acc[q][s] = fmaf(xqc, xj[s], acc[q][s]);
        }
    }
    float sqj[8];
    #pragma unroll
    for (int s = 0; s < 8; ++s) sqj[s] = sq[b * NN + t + s * 256];

    // dist in place: d = sq_i + sq_j - 2*inner  (same formula as reference)
    #pragma unroll
    for (int q = 0; q < QT; ++q) {
        float sqi = sqq[q];
        #pragma unroll
        for (int s = 0; s < 8; ++s)
            acc[q][s] = sqi + sqj[s] - 2.f * acc[q][s];
    }

    int lane = t & 63, wid = t >> 6;
    #pragma unroll
    for (int q = 0; q < QT; ++q) {
        int* orow = idx + (size_t)(b * NN + q0 + q) * KK;
        for (int r = 0; r < KK; ++r) {
            // local argmin over 8 register candidates (ties -> smaller j, since j ascends with s)
            float mv = acc[q][0]; int mj = t;
            #pragma unroll
            for (int s = 1; s < 8; ++s) {
                if (acc[q][s] < mv) { mv = acc[q][s]; mj = s * 256 + t; }
            }
            // wave argmin (lexicographic: value, then smaller index)
            #pragma unroll
            for (int off = 32; off >= 1; off >>= 1) {
                float ov = __shfl_xor(mv, off);
                int oj = __shfl_xor(mj, off);
                if (ov < mv || (ov == mv && oj < mj)) { mv = ov; mj = oj; }
            }
            if (lane == 0) { red_v[wid] = mv; red_j[wid] = mj; }
            __syncthreads();
            if (t == 0) {
                #pragma unroll
                for (int w = 1; w < 4; ++w) {
                    if (red_v[w] < mv || (red_v[w] == mv && red_j[w] < mj)) {
                        mv = red_v[w]; mj = red_j[w];
                    }
                }
                win = mj;
                orow[r] = mj;
            }
            __syncthreads();
            int wj = win;
            if ((wj & 255) == t) {
                int sw = wj >> 8;
                #pragma unroll
                for (int s = 0; s < 8; ++s)
                    if (s == sw) acc[q][s] = __builtin_inff();
            }
        }
    }
}

// ---------------- p/t: p = Wn·x, t = (Wc-Wn)·x ----------------
template<int C, int OT>
__global__ __launch_bounds__(256) void pt_kernel(const float* __restrict__ x,
                                                 const float* __restrict__ W,
                                                 float* __restrict__ p,
                                                 float* __restrict__ tt,
                                                 int O) {
    const int NB = NN / 256;
    int blk = blockIdx.x;
    int nb = blk % NB;
    int rest = blk / NB;
    int nob = O / OT;
    int ob = rest % nob;
    int b = rest / nob;
    int t = threadIdx.x;
    int n = nb * 256 + t;
    __shared__ float wn[OT][C], wd[OT][C];
    for (int e = t; e < OT * C; e += 256) {
        int o = e / C, c = e - o * C;
        float a = W[(size_t)(ob * OT + o) * (2 * C) + c];
        float b2 = W[(size_t)(ob * OT + o) * (2 * C) + C + c];
        wn[o][c] = a;
        wd[o][c] = b2 - a;
    }
    __syncthreads();
    float ap[OT], at[OT];
    #pragma unroll
    for (int o = 0; o < OT; ++o) { ap[o] = 0.f; at[o] = 0.f; }
    const float* xb = x + (size_t)b * C * NN + n;
    for (int c = 0; c < C; ++c) {
        float xv = xb[(size_t)c * NN];
        #pragma unroll
        for (int o = 0; o < OT; ++o) {
            ap[o] = fmaf(wn[o][c], xv, ap[o]);
            at[o] = fmaf(wd[o][c], xv, at[o]);
        }
    }
    size_t base = ((size_t)b * O + ob * OT) * NN + n;
    #pragma unroll
    for (int o = 0; o < OT; ++o) {
        p[base + (size_t)o * NN] = ap[o];
        tt[base + (size_t)o * NN] = at[o];
    }
}

// ---------------- edge max: out[b,o,i] = max_k lrelu(scale*(p[j]+t_i)+beta) ----------------
__global__ __launch_bounds__(256) void edge_kernel(const float* __restrict__ p,
                                                   const float* __restrict__ tt,
                                                   const int* __restrict__ idx,
                                                   const float* __restrict__ g,
                                                   const float* __restrict__ be,
                                                   float* __restrict__ out, int O) {
    int b = blockIdx.x / O, o = blockIdx.x - b * O;
    __shared__ float pl[NN];
    const float* pr = p + ((size_t)b * O + o) * NN;
    for (int e = threadIdx.x; e < NN; e += 256) pl[e] = pr[e];
    __syncthreads();
    float scale = g[o] / sqrtf(1.f + 1e-5f);
    float beta = be[o];
    const float* tr = tt + ((size_t)b * O + o) * NN;
    float* orow = out + ((size_t)b * O + o) * NN;
    for (int i = threadIdx.x; i < NN; i += 256) {
        float ti = tr[i];
        const int* ir = idx + (size_t)(b * NN + i) * KK;
        float m = -__builtin_inff();
        #pragma unroll
        for (int k = 0; k < KK; ++k) {
            float y = pl[ir[k]] + ti;
            m = fmaxf(m, lrelu(fmaf(scale, y, beta)));
        }
        orow[i] = m;
    }
}

// ---------------- final: z[b,o,n]=lrelu(scale*(W5[o,:]·x4[b,:,n])+beta); partial max over n-chunk ----------------
__global__ __launch_bounds__(256) void final_kernel(const float* __restrict__ x4,
                                                    const float* __restrict__ W5,
                                                    const float* __restrict__ g,
                                                    const float* __restrict__ be,
                                                    float* __restrict__ partial) {
    const int CC = 256, OT = 64, NCH = 8, NL = NN / NCH; // NL=256
    int blk = blockIdx.x;
    int nc = blk % NCH;
    int rest = blk / NCH;
    int ob = rest % (1024 / OT);
    int b = rest / (1024 / OT);
    int t = threadIdx.x;
    int n = nc * NL + t;
    __shared__ float wl[OT][64];
    __shared__ float redm[4][OT];
    float acc[OT];
    #pragma unroll
    for (int o = 0; o < OT; ++o) acc[o] = 0.f;
    for (int c0 = 0; c0 < CC; c0 += 64) {
        __syncthreads();
        for (int e = t; e < OT * 64; e += 256) {
            int o = e >> 6, c = e & 63;
            wl[o][c] = W5[(size_t)(ob * OT + o) * CC + c0 + c];
        }
        __syncthreads();
        const float* xb = x4 + (size_t)b * CC * NN + (size_t)c0 * NN + n;
        for (int c = 0; c < 64; ++c) {
            float xv = xb[(size_t)c * NN];
            #pragma unroll
            for (int o = 0; o < OT; ++o) acc[o] = fmaf(wl[o][c], xv, acc[o]);
        }
    }
    float rs = 1.f / sqrtf(1.f + 1e-5f);
    int lane = t & 63, wid = t >> 6;
    #pragma unroll
    for (int o = 0; o < OT; ++o) {
        float z = lrelu(fmaf(g[ob * OT + o] * rs, acc[o], be[ob * OT + o]));
        #pragma unroll
        for (int off = 32; off >= 1; off >>= 1)
            z = fmaxf(z, __shfl_xor(z, off));
        if (lane == 0) redm[wid][o] = z;
    }
    __syncthreads();
    if (t < OT) {
        float m = fmaxf(fmaxf(redm[0][t], redm[1][t]), fmaxf(redm[2][t], redm[3][t]));
        partial[(size_t)((b * 16 + ob) * OT + t) * NCH + nc] = m;
    }
}

__global__ __launch_bounds__(256) void reduce8_kernel(const float* __restrict__ partial,
                                                      float* __restrict__ out) {
    int i = blockIdx.x * 256 + threadIdx.x;
    if (i >= BB * 1024) return;
    float m = -__builtin_inff();
    #pragma unroll
    for (int k = 0; k < 8; ++k) m = fmaxf(m, partial[(size_t)i * 8 + k]);
    out[i] = m;
}

extern "C" void kernel_launch(void* const* d_in, const int* in_sizes, int n_in,
                              void* d_out, int out_size, void* d_ws, size_t ws_size,
                              hipStream_t stream) {
    const float* x  = (const float*)d_in[0];
    const float* W1 = (const float*)d_in[1];
    const float* g1 = (const float*)d_in[2];
    const float* b1 = (const float*)d_in[3];
    const float* W2 = (const float*)d_in[4];
    const float* g2 = (const float*)d_in[5];
    const float* b2 = (const float*)d_in[6];
    const float* W3 = (const float*)d_in[7];
    const float* g3 = (const float*)d_in[8];
    const float* b3 = (const float*)d_in[9];
    const float* W4 = (const float*)d_in[10];
    const float* g4 = (const float*)d_in[11];
    const float* b4 = (const float*)d_in[12];
    const float* W5 = (const float*)d_in[13];
    const float* g5 = (const float*)d_in[14];
    const float* b5 = (const float*)d_in[15];

    float* ws = (float*)d_ws;
    float* sq      = ws;                       // 8192
    int*   idx     = (int*)(ws + 8192);        // 4*2048*20 = 163840
    float* x1      = ws + 8192 + 163840;       // 524288
    float* x2      = x1 + 524288;              // 524288
    float* x3      = x2 + 524288;              // 1048576
    float* x4      = x3 + 1048576;             // 2097152
    float* p       = x4 + 2097152;             // 2097152
    float* tt      = p + 2097152;              // 2097152
    float* partial = tt + 2097152;             // 32768

    dim3 blk(256);

    // ---- layer 1: C=3, O=64 ----
    sq_kernel<3><<<32, blk, 0, stream>>>(x, sq);
    knn_kernel<3><<<BB * (NN / 8), blk, 0, stream>>>(x, sq, idx);
    pt_kernel<3, 16><<<BB * (64 / 16) * (NN / 256), blk, 0, stream>>>(x, W1, p, tt, 64);
    edge_kernel<<<BB * 64, blk, 0, stream>>>(p, tt, idx, g1, b1, x1, 64);

    // ---- layer 2: C=64, O=64 ----
    sq_kernel<64><<<32, blk, 0, stream>>>(x1, sq);
    knn_kernel<64><<<BB * (NN / 8), blk, 0, stream>>>(x1, sq, idx);
    pt_kernel<64, 16><<<BB * (64 / 16) * (NN / 256), blk, 0, stream>>>(x1, W2, p, tt, 64);
    edge_kernel<<<BB * 64, blk, 0, stream>>>(p, tt, idx, g2, b2, x2, 64);

    // ---- layer 3: C=64, O=128 ----
    sq_kernel<64><<<32, blk, 0, stream>>>(x2, sq);
    knn_kernel<64><<<BB * (NN / 8), blk, 0, stream>>>(x2, sq, idx);
    pt_kernel<64, 16><<<BB * (128 / 16) * (NN / 256), blk, 0, stream>>>(x2, W3, p, tt, 128);
    edge_kernel<<<BB * 128, blk, 0, stream>>>(p, tt, idx, g3, b3, x3, 128);

    // ---- layer 4: C=128, O=256 ----
    sq_kernel<128><<<32, blk, 0, stream>>>(x3, sq);
    knn_kernel<128><<<BB * (NN / 8), blk, 0, stream>>>(x3, sq, idx);
    pt_kernel<128, 16><<<BB * (256 / 16) * (NN / 256), blk, 0, stream>>>(x3, W4, p, tt, 256);
    edge_kernel<<<BB * 256, blk, 0, stream>>>(p, tt, idx, g4, b4, x4, 256);

    // ---- layer 5: C=256, O=1024, fused max over n ----
    final_kernel<<<BB * (1024 / 64) * 8, blk, 0, stream>>>(x4, W5, g5, b5, partial);
    reduce8_kernel<<<(BB * 1024 + 255) / 256, blk, 0, stream>>>(partial, d_out ? (float*)d_out : nullptr);
}

// Round 2
// 845.315 us; speedup vs baseline: 1.6808x; 1.6808x over previous
//
#include <hip/hip_runtime.h>
#include <math.h>

#define BB 4
#define NN 2048
#define KK 20

static __device__ __forceinline__ float lrelu(float z) {
    return z >= 0.f ? z : 0.2f * z;
}

// ---------------- sq: per-point squared norm ----------------
template<int C>
__global__ __launch_bounds__(256) void sq_kernel(const float* __restrict__ x,
                                                 float* __restrict__ sq) {
    int i = blockIdx.x * 256 + threadIdx.x;
    if (i >= BB * NN) return;
    int b = i / NN, n = i - b * NN;
    const float* xb = x + (size_t)b * C * NN + n;
    float s = 0.f;
    #pragma unroll
    for (int c = 0; c < C; ++c) {
        float v = xb[(size_t)c * NN];
        s = fmaf(v, v, s);
    }
    sq[i] = s;
}

// ---------------- knn: top-20 smallest distance indices ----------------
// Block = 256 threads handles (b, 8 consecutive queries).
// Phase 1 (block-wide): distances via register tiling (8 FMA per xj load).
// Phase 2 (wave-local): distances redistributed through LDS; each wave owns
// 2 queries with 32 candidates/lane in registers. Selection = 20 rounds of
// shfl-only lexicographic argmin — ZERO barriers (vs 320 before).
template<int C>
__global__ __launch_bounds__(256) void knn_kernel(const float* __restrict__ x,
                                                  const float* __restrict__ sq,
                                                  int* __restrict__ idx) {
    const int QT = 8;
    __shared__ float dl[QT][NN];   // 64 KB
    __shared__ float xq[QT][C];
    __shared__ float sqq[QT];
    int blk = blockIdx.x;
    int b = blk / (NN / QT);
    int q0 = (blk - b * (NN / QT)) * QT;
    int t = threadIdx.x;
    int lane = t & 63, wid = t >> 6;

    const float* xb = x + (size_t)b * C * NN;
    for (int e = t; e < QT * C; e += 256) {
        int q = e / C, c = e - q * C;
        xq[q][c] = xb[(size_t)c * NN + q0 + q];
    }
    if (t < QT) sqq[t] = sq[b * NN + q0 + t];
    __syncthreads();

    float acc[QT][8];
    #pragma unroll
    for (int q = 0; q < QT; ++q)
        #pragma unroll
        for (int s = 0; s < 8; ++s) acc[q][s] = 0.f;

    for (int c = 0; c < C; ++c) {
        float xj[8];
        #pragma unroll
        for (int s = 0; s < 8; ++s) xj[s] = xb[(size_t)c * NN + t + s * 256];
        #pragma unroll
        for (int q = 0; q < QT; ++q) {
            float xqc = xq[q][c];
            #pragma unroll
            for (int s = 0; s < 8; ++s) acc[q][s] = fmaf(xqc, xj[s], acc[q][s]);
        }
    }
    float sqj[8];
    #pragma unroll
    for (int s = 0; s < 8; ++s) sqj[s] = sq[b * NN + t + s * 256];

    // d = sq_i + sq_j - 2*inner (exact same arithmetic as before — idx must not change)
    #pragma unroll
    for (int q = 0; q < QT; ++q) {
        float sqi = sqq[q];
        #pragma unroll
        for (int s = 0; s < 8; ++s)
            acc[q][s] = sqi + sqj[s] - 2.f * acc[q][s];
    }

    // redistribute: dl[q][j], j = s*256 + t (stride-256 writes, conflict-free)
    #pragma unroll
    for (int q = 0; q < QT; ++q)
        #pragma unroll
        for (int s = 0; s < 8; ++s)
            dl[q][s * 256 + t] = acc[q][s];
    __syncthreads();   // the ONLY barrier in the selection path

    // wave wid owns queries 2*wid, 2*wid+1; lane holds candidates j = s2*64+lane
    float cand[2][32];
    #pragma unroll
    for (int h = 0; h < 2; ++h)
        #pragma unroll
        for (int s2 = 0; s2 < 32; ++s2)
            cand[h][s2] = dl[2 * wid + h][s2 * 64 + lane];

    #pragma unroll
    for (int h = 0; h < 2; ++h) {
        int* orow = idx + (size_t)(b * NN + q0 + 2 * wid + h) * KK;
        #pragma unroll 1
        for (int r = 0; r < KK; ++r) {
            // local argmin over 32 register candidates; ascending s2 + strict < ->
            // smallest j within lane on ties
            float v = cand[h][0]; int si = 0;
            #pragma unroll
            for (int s2 = 1; s2 < 32; ++s2)
                if (cand[h][s2] < v) { v = cand[h][s2]; si = s2; }
            int j = si * 64 + lane;
            // wave argmin, lexicographic (value, then smaller index) — matches lax.top_k
            #pragma unroll
            for (int off = 32; off >= 1; off >>= 1) {
                float ov = __shfl_xor(v, off);
                int oj = __shfl_xor(j, off);
                if (ov < v || (ov == v && oj < j)) { v = ov; j = oj; }
            }
            if ((j & 63) == lane) {
                int sw = j >> 6;
                #pragma unroll
                for (int s2 = 0; s2 < 32; ++s2)
                    if (s2 == sw) cand[h][s2] = __builtin_inff();
            }
            if (lane == 0) orow[r] = j;
        }
    }
}

// ---------------- p/t: p = Wn·x, t = (Wc-Wn)·x ----------------
template<int C, int OT>
__global__ __launch_bounds__(256) void pt_kernel(const float* __restrict__ x,
                                                 const float* __restrict__ W,
                                                 float* __restrict__ p,
                                                 float* __restrict__ tt,
                                                 int O) {
    const int NB = NN / 256;
    int blk = blockIdx.x;
    int nb = blk % NB;
    int rest = blk / NB;
    int nob = O / OT;
    int ob = rest % nob;
    int b = rest / nob;
    int t = threadIdx.x;
    int n = nb * 256 + t;
    __shared__ float wn[OT][C], wd[OT][C];
    for (int e = t; e < OT * C; e += 256) {
        int o = e / C, c = e - o * C;
        float a = W[(size_t)(ob * OT + o) * (2 * C) + c];
        float b2 = W[(size_t)(ob * OT + o) * (2 * C) + C + c];
        wn[o][c] = a;
        wd[o][c] = b2 - a;
    }
    __syncthreads();
    float ap[OT], at[OT];
    #pragma unroll
    for (int o = 0; o < OT; ++o) { ap[o] = 0.f; at[o] = 0.f; }
    const float* xb = x + (size_t)b * C * NN + n;
    for (int c = 0; c < C; ++c) {
        float xv = xb[(size_t)c * NN];
        #pragma unroll
        for (int o = 0; o < OT; ++o) {
            ap[o] = fmaf(wn[o][c], xv, ap[o]);
            at[o] = fmaf(wd[o][c], xv, at[o]);
        }
    }
    size_t base = ((size_t)b * O + ob * OT) * NN + n;
    #pragma unroll
    for (int o = 0; o < OT; ++o) {
        p[base + (size_t)o * NN] = ap[o];
        tt[base + (size_t)o * NN] = at[o];
    }
}

// ---------------- edge max: out[b,o,i] = max_k lrelu(scale*(p[j]+t_i)+beta) ----------------
__global__ __launch_bounds__(256) void edge_kernel(const float* __restrict__ p,
                                                   const float* __restrict__ tt,
                                                   const int* __restrict__ idx,
                                                   const float* __restrict__ g,
                                                   const float* __restrict__ be,
                                                   float* __restrict__ out, int O) {
    int b = blockIdx.x / O, o = blockIdx.x - b * O;
    __shared__ float pl[NN];
    const float* pr = p + ((size_t)b * O + o) * NN;
    for (int e = threadIdx.x; e < NN; e += 256) pl[e] = pr[e];
    __syncthreads();
    float scale = g[o] / sqrtf(1.f + 1e-5f);
    float beta = be[o];
    const float* tr = tt + ((size_t)b * O + o) * NN;
    float* orow = out + ((size_t)b * O + o) * NN;
    for (int i = threadIdx.x; i < NN; i += 256) {
        float ti = tr[i];
        const int* ir = idx + (size_t)(b * NN + i) * KK;
        float m = -__builtin_inff();
        #pragma unroll
        for (int k = 0; k < KK; ++k) {
            float y = pl[ir[k]] + ti;
            m = fmaxf(m, lrelu(fmaf(scale, y, beta)));
        }
        orow[i] = m;
    }
}

// ---------------- transpose W5 [1024][256] -> W5T [256][1024] ----------------
__global__ __launch_bounds__(256) void transpose_kernel(const float* __restrict__ W,
                                                        float* __restrict__ WT) {
    __shared__ float tile[32][33];
    int c0 = blockIdx.x * 32, o0 = blockIdx.y * 32;
    int tx = threadIdx.x, ty = threadIdx.y;   // 32 x 8
    #pragma unroll
    for (int i = 0; i < 32; i += 8)
        tile[ty + i][tx] = W[(size_t)(o0 + ty + i) * 256 + c0 + tx];
    __syncthreads();
    #pragma unroll
    for (int i = 0; i < 32; i += 8)
        WT[(size_t)(c0 + ty + i) * 1024 + o0 + tx] = tile[tx][ty + i];
}

// ---------------- final: register-tiled GEMM + fused lrelu + max over n ----------------
// block tile 64o x 64n, thread tile 4o x 4n (16 accs, no spill).
// grid = b(4) * ob(16) * nb(32); partial[nb][b][1024] max-reduced by reduce32.
__global__ __launch_bounds__(256) void final_kernel(const float* __restrict__ x4,
                                                    const float* __restrict__ W5T,
                                                    const float* __restrict__ g,
                                                    const float* __restrict__ be,
                                                    float* __restrict__ partial) {
    const int CC = 256;
    __shared__ float xs[64][64];   // [c][n] 16 KB
    __shared__ float ws[64][64];   // [c][o] 16 KB
    int blk = blockIdx.x;
    int nb = blk & 31;
    int ob = (blk >> 5) & 15;
    int b  = blk >> 9;
    int t = threadIdx.x;
    int tn = t & 15, to = t >> 4;   // 16 n-groups x 16 o-groups

    float acc[4][4];   // [o][n]
    #pragma unroll
    for (int i = 0; i < 4; ++i)
        #pragma unroll
        for (int j = 0; j < 4; ++j) acc[i][j] = 0.f;

    for (int c0 = 0; c0 < CC; c0 += 64) {
        __syncthreads();
        #pragma unroll
        for (int e = t * 4; e < 64 * 64; e += 1024) {
            int c = e >> 6, n = e & 63;
            *(float4*)&xs[c][n] =
                *(const float4*)&x4[((size_t)b * CC + c0 + c) * NN + nb * 64 + n];
        }
        #pragma unroll
        for (int e = t * 4; e < 64 * 64; e += 1024) {
            int c = e >> 6, o = e & 63;
            *(float4*)&ws[c][o] =
                *(const float4*)&W5T[(size_t)(c0 + c) * 1024 + ob * 64 + o];
        }
        __syncthreads();
        for (int c = 0; c < 64; ++c) {
            float4 xv = *(float4*)&xs[c][tn * 4];
            float4 wv = *(float4*)&ws[c][to * 4];
            acc[0][0] = fmaf(wv.x, xv.x, acc[0][0]);
            acc[0][1] = fmaf(wv.x, xv.y, acc[0][1]);
            acc[0][2] = fmaf(wv.x, xv.z, acc[0][2]);
            acc[0][3] = fmaf(wv.x, xv.w, acc[0][3]);
            acc[1][0] = fmaf(wv.y, xv.x, acc[1][0]);
            acc[1][1] = fmaf(wv.y, xv.y, acc[1][1]);
            acc[1][2] = fmaf(wv.y, xv.z, acc[1][2]);
            acc[1][3] = fmaf(wv.y, xv.w, acc[1][3]);
            acc[2][0] = fmaf(wv.z, xv.x, acc[2][0]);
            acc[2][1] = fmaf(wv.z, xv.y, acc[2][1]);
            acc[2][2] = fmaf(wv.z, xv.z, acc[2][2]);
            acc[2][3] = fmaf(wv.z, xv.w, acc[2][3]);
            acc[3][0] = fmaf(wv.w, xv.x, acc[3][0]);
            acc[3][1] = fmaf(wv.w, xv.y, acc[3][1]);
            acc[3][2] = fmaf(wv.w, xv.z, acc[3][2]);
            acc[3][3] = fmaf(wv.w, xv.w, acc[3][3]);
        }
    }

    float rs = 1.f / sqrtf(1.f + 1e-5f);
    #pragma unroll
    for (int i = 0; i < 4; ++i) {
        int o = ob * 64 + to * 4 + i;
        float scale = g[o] * rs, beta = be[o];
        float m = -__builtin_inff();
        #pragma unroll
        for (int j = 0; j < 4; ++j)
            m = fmaxf(m, lrelu(fmaf(scale, acc[i][j], beta)));
        // reduce over the 16 n-groups (lanes sharing to, i.e. tn = lane&15)
        #pragma unroll
        for (int off = 8; off >= 1; off >>= 1)
            m = fmaxf(m, __shfl_xor(m, off));
        if (tn == 0)
            partial[(size_t)(nb * BB + b) * 1024 + o] = m;
    }
}

__global__ __launch_bounds__(256) void reduce32_kernel(const float* __restrict__ partial,
                                                       float* __restrict__ out) {
    int i = blockIdx.x * 256 + threadIdx.x;
    if (i >= BB * 1024) return;
    int b = i >> 10, o = i & 1023;
    float m = -__builtin_inff();
    #pragma unroll
    for (int nb = 0; nb < 32; ++nb)
        m = fmaxf(m, partial[(size_t)(nb * BB + b) * 1024 + o]);
    out[i] = m;
}

extern "C" void kernel_launch(void* const* d_in, const int* in_sizes, int n_in,
                              void* d_out, int out_size, void* d_ws, size_t ws_size,
                              hipStream_t stream) {
    const float* x  = (const float*)d_in[0];
    const float* W1 = (const float*)d_in[1];
    const float* g1 = (const float*)d_in[2];
    const float* b1 = (const float*)d_in[3];
    const float* W2 = (const float*)d_in[4];
    const float* g2 = (const float*)d_in[5];
    const float* b2 = (const float*)d_in[6];
    const float* W3 = (const float*)d_in[7];
    const float* g3 = (const float*)d_in[8];
    const float* b3 = (const float*)d_in[9];
    const float* W4 = (const float*)d_in[10];
    const float* g4 = (const float*)d_in[11];
    const float* b4 = (const float*)d_in[12];
    const float* W5 = (const float*)d_in[13];
    const float* g5 = (const float*)d_in[14];
    const float* b5 = (const float*)d_in[15];

    float* ws = (float*)d_ws;
    float* sq      = ws;                       // 8192
    int*   idx     = (int*)(ws + 8192);        // 163840 ints
    float* x1      = ws + 8192 + 163840;       // 524288
    float* x2      = x1 + 524288;              // 524288
    float* x3      = x2 + 524288;              // 1048576
    float* x4      = x3 + 1048576;             // 2097152
    float* p       = x4 + 2097152;             // 2097152
    float* tt      = p + 2097152;              // 2097152
    // p and tt are dead after edge layer 4 -> reuse for W5T and partial
    float* W5T     = p;                        // 262144 needed
    float* partial = tt;                       // 131072 needed

    dim3 blk(256);

    // ---- layer 1: C=3, O=64 ----
    sq_kernel<3><<<32, blk, 0, stream>>>(x, sq);
    knn_kernel<3><<<BB * (NN / 8), blk, 0, stream>>>(x, sq, idx);
    pt_kernel<3, 16><<<BB * (64 / 16) * (NN / 256), blk, 0, stream>>>(x, W1, p, tt, 64);
    edge_kernel<<<BB * 64, blk, 0, stream>>>(p, tt, idx, g1, b1, x1, 64);

    // ---- layer 2: C=64, O=64 ----
    sq_kernel<64><<<32, blk, 0, stream>>>(x1, sq);
    knn_kernel<64><<<BB * (NN / 8), blk, 0, stream>>>(x1, sq, idx);
    pt_kernel<64, 16><<<BB * (64 / 16) * (NN / 256), blk, 0, stream>>>(x1, W2, p, tt, 64);
    edge_kernel<<<BB * 64, blk, 0, stream>>>(p, tt, idx, g2, b2, x2, 64);

    // ---- layer 3: C=64, O=128 ----
    sq_kernel<64><<<32, blk, 0, stream>>>(x2, sq);
    knn_kernel<64><<<BB * (NN / 8), blk, 0, stream>>>(x2, sq, idx);
    pt_kernel<64, 16><<<BB * (128 / 16) * (NN / 256), blk, 0, stream>>>(x2, W3, p, tt, 128);
    edge_kernel<<<BB * 128, blk, 0, stream>>>(p, tt, idx, g3, b3, x3, 128);

    // ---- layer 4: C=128, O=256 ----
    sq_kernel<128><<<32, blk, 0, stream>>>(x3, sq);
    knn_kernel<128><<<BB * (NN / 8), blk, 0, stream>>>(x3, sq, idx);
    pt_kernel<128, 16><<<BB * (256 / 16) * (NN / 256), blk, 0, stream>>>(x3, W4, p, tt, 256);
    edge_kernel<<<BB * 256, blk, 0, stream>>>(p, tt, idx, g4, b4, x4, 256);

    // ---- layer 5: C=256, O=1024, fused max over n ----
    transpose_kernel<<<dim3(8, 32), dim3(32, 8), 0, stream>>>(W5, W5T);
    final_kernel<<<BB * 16 * 32, blk, 0, stream>>>(x4, W5T, g5, b5, partial);
    reduce32_kernel<<<16, blk, 0, stream>>>(partial, (float*)d_out);
}

// Round 3
// 720.241 us; speedup vs baseline: 1.9727x; 1.1737x over previous
//
#include <hip/hip_runtime.h>
#include <math.h>

#define BB 4
#define NN 2048
#define KK 20

static __device__ __forceinline__ float lrelu(float z) {
    return z >= 0.f ? z : 0.2f * z;
}

// ---------------- sq: per-point squared norm ----------------
template<int C>
__global__ __launch_bounds__(256) void sq_kernel(const float* __restrict__ x,
                                                 float* __restrict__ sq) {
    int i = blockIdx.x * 256 + threadIdx.x;
    if (i >= BB * NN) return;
    int b = i / NN, n = i - b * NN;
    const float* xb = x + (size_t)b * C * NN + n;
    float s = 0.f;
    #pragma unroll
    for (int c = 0; c < C; ++c) {
        float v = xb[(size_t)c * NN];
        s = fmaf(v, v, s);
    }
    sq[i] = s;
}

// 20 rounds of exact (d, j) lexicographic extraction over the wave.
// cand[s2] holds d for j = s2*64 + lane.
static __device__ __forceinline__ void select20(float (&cand)[32], int* orow, int lane) {
    #pragma unroll 1
    for (int r = 0; r < KK; ++r) {
        // local value min: tree (fminf fuses to v_min3)
        float m[16];
        #pragma unroll
        for (int i = 0; i < 16; ++i) m[i] = fminf(cand[i], cand[i + 16]);
        #pragma unroll
        for (int i = 0; i < 8; ++i) m[i] = fminf(m[i], m[i + 8]);
        #pragma unroll
        for (int i = 0; i < 4; ++i) m[i] = fminf(m[i], m[i + 4]);
        float v = fminf(fminf(m[0], m[1]), fminf(m[2], m[3]));
        // wave value min
        #pragma unroll
        for (int off = 32; off >= 1; off >>= 1)
            v = fminf(v, __shfl_xor(v, off));
        // smallest slot s2 in this lane with cand==v (descending chain, inline consts)
        int es = 64;
        #pragma unroll
        for (int s2 = 31; s2 >= 0; --s2)
            es = (cand[s2] == v) ? s2 : es;
        int enc = (es << 6) | lane;   // es==64 -> 4096|lane sentinel > any valid j
        // smallest j among d==v across the wave
        #pragma unroll
        for (int off = 32; off >= 1; off >>= 1)
            enc = min(enc, __shfl_xor(enc, off));
        // winner invalidates its slot
        if (lane == (enc & 63)) {
            int sw = enc >> 6;
            #pragma unroll
            for (int s2 = 0; s2 < 32; ++s2)
                if (s2 == sw) cand[s2] = __builtin_inff();
        }
        if (lane == 0) orow[r] = enc;
    }
}

// ---------------- knn: top-20 smallest distance indices ----------------
// Block = 256 threads handles (b, 8 consecutive queries).
// Distance phase: block-wide register tiling (8 FMA per xj load), bit-identical
// arithmetic to the passing R2 version.
// Selection: TWO passes of 4 queries; each wave owns 1 query per pass with 32
// candidates/lane in registers. dl is 32 KB -> 4 blocks/CU (2x occupancy).
// Pass-1 LDS writes are issued before pass-0's selection loop to hide them.
template<int C>
__global__ __launch_bounds__(256, 4) void knn_kernel(const float* __restrict__ x,
                                                     const float* __restrict__ sq,
                                                     int* __restrict__ idx) {
    const int QT = 8;
    __shared__ float dl[4][NN];   // 32 KB
    __shared__ float xq[QT][C];
    __shared__ float sqq[QT];
    int blk = blockIdx.x;
    int b = blk / (NN / QT);
    int q0 = (blk - b * (NN / QT)) * QT;
    int t = threadIdx.x;
    int lane = t & 63, wid = t >> 6;

    const float* xb = x + (size_t)b * C * NN;
    for (int e = t; e < QT * C; e += 256) {
        int q = e / C, c = e - q * C;
        xq[q][c] = xb[(size_t)c * NN + q0 + q];
    }
    if (t < QT) sqq[t] = sq[b * NN + q0 + t];
    __syncthreads();

    float acc[QT][8];
    #pragma unroll
    for (int q = 0; q < QT; ++q)
        #pragma unroll
        for (int s = 0; s < 8; ++s) acc[q][s] = 0.f;

    for (int c = 0; c < C; ++c) {
        float xj[8];
        #pragma unroll
        for (int s = 0; s < 8; ++s) xj[s] = xb[(size_t)c * NN + t + s * 256];
        #pragma unroll
        for (int q = 0; q < QT; ++q) {
            float xqc = xq[q][c];
            #pragma unroll
            for (int s = 0; s < 8; ++s) acc[q][s] = fmaf(xqc, xj[s], acc[q][s]);
        }
    }
    float sqj[8];
    #pragma unroll
    for (int s = 0; s < 8; ++s) sqj[s] = sq[b * NN + t + s * 256];

    // d = sq_i + sq_j - 2*inner (same arithmetic as R2 — neighbor sets must not move)
    #pragma unroll
    for (int q = 0; q < QT; ++q) {
        float sqi = sqq[q];
        #pragma unroll
        for (int s = 0; s < 8; ++s)
            acc[q][s] = sqi + sqj[s] - 2.f * acc[q][s];
    }

    // ---- pass 0: queries q0+0..3 ----
    #pragma unroll
    for (int q = 0; q < 4; ++q)
        #pragma unroll
        for (int s = 0; s < 8; ++s)
            dl[q][s * 256 + t] = acc[q][s];
    __syncthreads();

    float cand[32];
    #pragma unroll
    for (int s2 = 0; s2 < 32; ++s2)
        cand[s2] = dl[wid][s2 * 64 + lane];
    __syncthreads();   // all waves have their cand; dl may be overwritten

    // pass-1 writes issued now — they complete under pass-0's selection
    #pragma unroll
    for (int q = 0; q < 4; ++q)
        #pragma unroll
        for (int s = 0; s < 8; ++s)
            dl[q][s * 256 + t] = acc[4 + q][s];

    select20(cand, idx + (size_t)(b * NN + q0 + wid) * KK, lane);

    // ---- pass 1: queries q0+4..7 ----
    __syncthreads();   // pass-1 writes visible
    #pragma unroll
    for (int s2 = 0; s2 < 32; ++s2)
        cand[s2] = dl[wid][s2 * 64 + lane];

    select20(cand, idx + (size_t)(b * NN + q0 + 4 + wid) * KK, lane);
}

// ---------------- p/t: p = Wn·x, t = (Wc-Wn)·x ----------------
template<int C, int OT>
__global__ __launch_bounds__(256) void pt_kernel(const float* __restrict__ x,
                                                 const float* __restrict__ W,
                                                 float* __restrict__ p,
                                                 float* __restrict__ tt,
                                                 int O) {
    const int NB = NN / 256;
    int blk = blockIdx.x;
    int nb = blk % NB;
    int rest = blk / NB;
    int nob = O / OT;
    int ob = rest % nob;
    int b = rest / nob;
    int t = threadIdx.x;
    int n = nb * 256 + t;
    __shared__ float wn[OT][C], wd[OT][C];
    for (int e = t; e < OT * C; e += 256) {
        int o = e / C, c = e - o * C;
        float a = W[(size_t)(ob * OT + o) * (2 * C) + c];
        float b2 = W[(size_t)(ob * OT + o) * (2 * C) + C + c];
        wn[o][c] = a;
        wd[o][c] = b2 - a;
    }
    __syncthreads();
    float ap[OT], at[OT];
    #pragma unroll
    for (int o = 0; o < OT; ++o) { ap[o] = 0.f; at[o] = 0.f; }
    const float* xb = x + (size_t)b * C * NN + n;
    for (int c = 0; c < C; ++c) {
        float xv = xb[(size_t)c * NN];
        #pragma unroll
        for (int o = 0; o < OT; ++o) {
            ap[o] = fmaf(wn[o][c], xv, ap[o]);
            at[o] = fmaf(wd[o][c], xv, at[o]);
        }
    }
    size_t base = ((size_t)b * O + ob * OT) * NN + n;
    #pragma unroll
    for (int o = 0; o < OT; ++o) {
        p[base + (size_t)o * NN] = ap[o];
        tt[base + (size_t)o * NN] = at[o];
    }
}

// ---------------- edge max: out[b,o,i] = max_k lrelu(scale*(p[j]+t_i)+beta) ----------------
__global__ __launch_bounds__(256) void edge_kernel(const float* __restrict__ p,
                                                   const float* __restrict__ tt,
                                                   const int* __restrict__ idx,
                                                   const float* __restrict__ g,
                                                   const float* __restrict__ be,
                                                   float* __restrict__ out, int O) {
    int b = blockIdx.x / O, o = blockIdx.x - b * O;
    __shared__ float pl[NN];
    const float* pr = p + ((size_t)b * O + o) * NN;
    for (int e = threadIdx.x; e < NN; e += 256) pl[e] = pr[e];
    __syncthreads();
    float scale = g[o] / sqrtf(1.f + 1e-5f);
    float beta = be[o];
    const float* tr = tt + ((size_t)b * O + o) * NN;
    float* orow = out + ((size_t)b * O + o) * NN;
    for (int i = threadIdx.x; i < NN; i += 256) {
        float ti = tr[i];
        const int4* ir4 = (const int4*)(idx + (size_t)(b * NN + i) * KK);
        int4 w0 = ir4[0], w1 = ir4[1], w2 = ir4[2], w3 = ir4[3], w4 = ir4[4];
        float m = -__builtin_inff();
        int js[20] = {w0.x, w0.y, w0.z, w0.w, w1.x, w1.y, w1.z, w1.w,
                      w2.x, w2.y, w2.z, w2.w, w3.x, w3.y, w3.z, w3.w,
                      w4.x, w4.y, w4.z, w4.w};
        #pragma unroll
        for (int k = 0; k < KK; ++k) {
            float y = pl[js[k]] + ti;
            m = fmaxf(m, lrelu(fmaf(scale, y, beta)));
        }
        orow[i] = m;
    }
}

// ---------------- transpose W5 [1024][256] -> W5T [256][1024] ----------------
__global__ __launch_bounds__(256) void transpose_kernel(const float* __restrict__ W,
                                                        float* __restrict__ WT) {
    __shared__ float tile[32][33];
    int c0 = blockIdx.x * 32, o0 = blockIdx.y * 32;
    int tx = threadIdx.x, ty = threadIdx.y;   // 32 x 8
    #pragma unroll
    for (int i = 0; i < 32; i += 8)
        tile[ty + i][tx] = W[(size_t)(o0 + ty + i) * 256 + c0 + tx];
    __syncthreads();
    #pragma unroll
    for (int i = 0; i < 32; i += 8)
        WT[(size_t)(c0 + ty + i) * 1024 + o0 + tx] = tile[tx][ty + i];
}

// ---------------- final: register-tiled GEMM + fused lrelu + max over n ----------------
__global__ __launch_bounds__(256) void final_kernel(const float* __restrict__ x4,
                                                    const float* __restrict__ W5T,
                                                    const float* __restrict__ g,
                                                    const float* __restrict__ be,
                                                    float* __restrict__ partial) {
    const int CC = 256;
    __shared__ float xs[64][64];
    __shared__ float ws[64][64];
    int blk = blockIdx.x;
    int nb = blk & 31;
    int ob = (blk >> 5) & 15;
    int b  = blk >> 9;
    int t = threadIdx.x;
    int tn = t & 15, to = t >> 4;

    float acc[4][4];
    #pragma unroll
    for (int i = 0; i < 4; ++i)
        #pragma unroll
        for (int j = 0; j < 4; ++j) acc[i][j] = 0.f;

    for (int c0 = 0; c0 < CC; c0 += 64) {
        __syncthreads();
        #pragma unroll
        for (int e = t * 4; e < 64 * 64; e += 1024) {
            int c = e >> 6, n = e & 63;
            *(float4*)&xs[c][n] =
                *(const float4*)&x4[((size_t)b * CC + c0 + c) * NN + nb * 64 + n];
        }
        #pragma unroll
        for (int e = t * 4; e < 64 * 64; e += 1024) {
            int c = e >> 6, o = e & 63;
            *(float4*)&ws[c][o] =
                *(const float4*)&W5T[(size_t)(c0 + c) * 1024 + ob * 64 + o];
        }
        __syncthreads();
        for (int c = 0; c < 64; ++c) {
            float4 xv = *(float4*)&xs[c][tn * 4];
            float4 wv = *(float4*)&ws[c][to * 4];
            acc[0][0] = fmaf(wv.x, xv.x, acc[0][0]);
            acc[0][1] = fmaf(wv.x, xv.y, acc[0][1]);
            acc[0][2] = fmaf(wv.x, xv.z, acc[0][2]);
            acc[0][3] = fmaf(wv.x, xv.w, acc[0][3]);
            acc[1][0] = fmaf(wv.y, xv.x, acc[1][0]);
            acc[1][1] = fmaf(wv.y, xv.y, acc[1][1]);
            acc[1][2] = fmaf(wv.y, xv.z, acc[1][2]);
            acc[1][3] = fmaf(wv.y, xv.w, acc[1][3]);
            acc[2][0] = fmaf(wv.z, xv.x, acc[2][0]);
            acc[2][1] = fmaf(wv.z, xv.y, acc[2][1]);
            acc[2][2] = fmaf(wv.z, xv.z, acc[2][2]);
            acc[2][3] = fmaf(wv.z, xv.w, acc[2][3]);
            acc[3][0] = fmaf(wv.w, xv.x, acc[3][0]);
            acc[3][1] = fmaf(wv.w, xv.y, acc[3][1]);
            acc[3][2] = fmaf(wv.w, xv.z, acc[3][2]);
            acc[3][3] = fmaf(wv.w, xv.w, acc[3][3]);
        }
    }

    float rs = 1.f / sqrtf(1.f + 1e-5f);
    #pragma unroll
    for (int i = 0; i < 4; ++i) {
        int o = ob * 64 + to * 4 + i;
        float scale = g[o] * rs, beta = be[o];
        float m = -__builtin_inff();
        #pragma unroll
        for (int j = 0; j < 4; ++j)
            m = fmaxf(m, lrelu(fmaf(scale, acc[i][j], beta)));
        #pragma unroll
        for (int off = 8; off >= 1; off >>= 1)
            m = fmaxf(m, __shfl_xor(m, off));
        if (tn == 0)
            partial[(size_t)(nb * BB + b) * 1024 + o] = m;
    }
}

__global__ __launch_bounds__(256) void reduce32_kernel(const float* __restrict__ partial,
                                                       float* __restrict__ out) {
    int i = blockIdx.x * 256 + threadIdx.x;
    if (i >= BB * 1024) return;
    int b = i >> 10, o = i & 1023;
    float m = -__builtin_inff();
    #pragma unroll
    for (int nb = 0; nb < 32; ++nb)
        m = fmaxf(m, partial[(size_t)(nb * BB + b) * 1024 + o]);
    out[i] = m;
}

extern "C" void kernel_launch(void* const* d_in, const int* in_sizes, int n_in,
                              void* d_out, int out_size, void* d_ws, size_t ws_size,
                              hipStream_t stream) {
    const float* x  = (const float*)d_in[0];
    const float* W1 = (const float*)d_in[1];
    const float* g1 = (const float*)d_in[2];
    const float* b1 = (const float*)d_in[3];
    const float* W2 = (const float*)d_in[4];
    const float* g2 = (const float*)d_in[5];
    const float* b2 = (const float*)d_in[6];
    const float* W3 = (const float*)d_in[7];
    const float* g3 = (const float*)d_in[8];
    const float* b3 = (const float*)d_in[9];
    const float* W4 = (const float*)d_in[10];
    const float* g4 = (const float*)d_in[11];
    const float* b4 = (const float*)d_in[12];
    const float* W5 = (const float*)d_in[13];
    const float* g5 = (const float*)d_in[14];
    const float* b5 = (const float*)d_in[15];

    float* ws = (float*)d_ws;
    float* sq      = ws;                       // 8192
    int*   idx     = (int*)(ws + 8192);        // 163840 ints
    float* x1      = ws + 8192 + 163840;       // 524288
    float* x2      = x1 + 524288;              // 524288
    float* x3      = x2 + 524288;              // 1048576
    float* x4      = x3 + 1048576;             // 2097152
    float* p       = x4 + 2097152;             // 2097152
    float* tt      = p + 2097152;              // 2097152
    float* W5T     = p;                        // reuse (dead after layer 4)
    float* partial = tt;                       // reuse

    dim3 blk(256);

    // ---- layer 1: C=3, O=64 ----
    sq_kernel<3><<<32, blk, 0, stream>>>(x, sq);
    knn_kernel<3><<<BB * (NN / 8), blk, 0, stream>>>(x, sq, idx);
    pt_kernel<3, 16><<<BB * (64 / 16) * (NN / 256), blk, 0, stream>>>(x, W1, p, tt, 64);
    edge_kernel<<<BB * 64, blk, 0, stream>>>(p, tt, idx, g1, b1, x1, 64);

    // ---- layer 2: C=64, O=64 ----
    sq_kernel<64><<<32, blk, 0, stream>>>(x1, sq);
    knn_kernel<64><<<BB * (NN / 8), blk, 0, stream>>>(x1, sq, idx);
    pt_kernel<64, 16><<<BB * (64 / 16) * (NN / 256), blk, 0, stream>>>(x1, W2, p, tt, 64);
    edge_kernel<<<BB * 64, blk, 0, stream>>>(p, tt, idx, g2, b2, x2, 64);

    // ---- layer 3: C=64, O=128 ----
    sq_kernel<64><<<32, blk, 0, stream>>>(x2, sq);
    knn_kernel<64><<<BB * (NN / 8), blk, 0, stream>>>(x2, sq, idx);
    pt_kernel<64, 16><<<BB * (128 / 16) * (NN / 256), blk, 0, stream>>>(x2, W3, p, tt, 128);
    edge_kernel<<<BB * 128, blk, 0, stream>>>(p, tt, idx, g3, b3, x3, 128);

    // ---- layer 4: C=128, O=256 ----
    sq_kernel<128><<<32, blk, 0, stream>>>(x3, sq);
    knn_kernel<128><<<BB * (NN / 8), blk, 0, stream>>>(x3, sq, idx);
    pt_kernel<128, 16><<<BB * (256 / 16) * (NN / 256), blk, 0, stream>>>(x3, W4, p, tt, 256);
    edge_kernel<<<BB * 256, blk, 0, stream>>>(p, tt, idx, g4, b4, x4, 256);

    // ---- layer 5: C=256, O=1024, fused max over n ----
    transpose_kernel<<<dim3(8, 32), dim3(32, 8), 0, stream>>>(W5, W5T);
    final_kernel<<<BB * 16 * 32, blk, 0, stream>>>(x4, W5T, g5, b5, partial);
    reduce32_kernel<<<16, blk, 0, stream>>>(partial, (float*)d_out);
}